// Round 17
// baseline (126.722 us; speedup 1.0000x reference)
//
#include <hip/hip_runtime.h>
#include <hip/hip_bf16.h>

// Fused Swin window attention for MI355X (gfx950) — round 17: 8-wave blocks.
// Session pattern: geometry changes win (r4, r9), scheduling tweaks lose
// (r10-r15). Last unexplored geometry axis: BLOCK SIZE. r9's occupancy cap
// is LDS/block (44KB, dominated by the 34KB x tile per 4-wave block).
// r17: 512-thread blocks (8 waves), ONE head per wave:
//   * per-wave fragments 96 -> 48 VGPR, per-wave MFMA 576 -> 288.
//   * LDS = x(33,792B) + 8 x 2,560B scratch = 54,272 B -> 2 blocks/CU
//     guaranteed (16 waves/CU), 3 blocks/CU (24 waves, 75% occ) if the
//     compiler lands <=85 VGPR (r9's same-shape code was 84).
//   * __launch_bounds__(512,4): safe 128-VGPR cap, no forced squeeze (r10
//     lesson). Index algebra = r9 with the hh loop removed (w*64 -> w*32).

typedef __attribute__((ext_vector_type(8))) short bf16x8;
typedef __attribute__((ext_vector_type(4))) float f32x4;

__device__ __forceinline__ f32x4 mfma16(bf16x8 a, bf16x8 b, f32x4 c) {
  return __builtin_amdgcn_mfma_f32_16x16x32_bf16(a, b, c, 0, 0, 0);
}

__device__ __forceinline__ unsigned short f2bf(float f) {
  __hip_bfloat16 h = __float2bfloat16(f);
  return *reinterpret_cast<unsigned short*>(&h);
}

__device__ __forceinline__ uint2 pack4(float a, float b, float c, float d) {
  union { unsigned short u[4]; uint2 v; } pk;
  pk.u[0] = f2bf(a); pk.u[1] = f2bf(b); pk.u[2] = f2bf(c); pk.u[3] = f2bf(d);
  return pk.v;
}

#define LOG2E 1.4426950408889634f
#define EXPSCALE (0.17677669529663687f * 1.4426950408889634f)

// LDS layout (ushort elements); row strides multiples of 8 elem (16B) for b128.
#define XO  264           // x / oh region row stride (64 rows)
#define RTS 40            // per-wave RT scratch row stride (32 rows used)
#define PS  72            // P scratch row stride (16 rows)
#define RT_ELEMS 1280     // per-wave scratch: 32x40 (covers P's 16x72=1152)
#define OFF_RT 16896      // 64*264
#define SMEM_ELTS 27136   // 16896 + 8*1280 = 54,272 B

// Weight tiled layout: elem(n,k) -> ((((n>>4)*8+(k>>5))*4+((k>>3)&3))*16+(n&15))*8+(k&7)
__global__ void prep_kernel(const float* __restrict__ w_qkv,
                            const float* __restrict__ w_out,
                            const float* __restrict__ pos_emb,
                            unsigned short* __restrict__ wqkvT,
                            unsigned short* __restrict__ woutT,
                            float* __restrict__ bias64) {
  const int stride = gridDim.x * blockDim.x;
  const int tid = blockIdx.x * blockDim.x + threadIdx.x;
  for (int i = tid; i < 768 * 256; i += stride) {
    int n = i >> 8, k = i & 255;
    int off = ((((n >> 4) * 8 + (k >> 5)) * 4 + ((k >> 3) & 3)) * 16 + (n & 15)) * 8 + (k & 7);
    wqkvT[off] = f2bf(w_qkv[k * 768 + n]);
  }
  for (int i = tid; i < 256 * 256; i += stride) {
    int n = i >> 8, k = i & 255;
    int off = ((((n >> 4) * 8 + (k >> 5)) * 4 + ((k >> 3) & 3)) * 16 + (n & 15)) * 8 + (k & 7);
    woutT[off] = f2bf(w_out[k * 256 + n]);
  }
  for (int i = tid; i < 64 * 64; i += stride) {
    int a = i >> 6, b = i & 63;
    int d0 = (b >> 3) - (a >> 3) + 7;
    int d1 = (b & 7) - (a & 7) + 7;
    bias64[i] = pos_emb[d0 * 15 + d1] * LOG2E;   // pre-scaled for exp2
  }
}

// 64px x 32col GEMM slice. SWAP=true: acc = mfma(w, x) -> (feat row, px col).
// SWAP=false: acc = mfma(x, w) -> (px row, feat col).
template <bool SWAP>
__device__ __forceinline__ void gemm32(f32x4 (&acc)[4][2],
                                       const unsigned short* __restrict__ a_lds,
                                       const unsigned short* __restrict__ wT,
                                       int col0, int l15, int lq) {
  const f32x4 zero4 = {0.f, 0.f, 0.f, 0.f};
#pragma unroll
  for (int rt = 0; rt < 4; ++rt)
#pragma unroll
    for (int ct = 0; ct < 2; ++ct) acc[rt][ct] = zero4;
#pragma unroll
  for (int kk = 0; kk < 8; ++kk) {
    bf16x8 a[4], b[2];
#pragma unroll
    for (int rt = 0; rt < 4; ++rt)
      a[rt] = *(const bf16x8*)&a_lds[(rt * 16 + l15) * XO + kk * 32 + lq * 8];
#pragma unroll
    for (int ct = 0; ct < 2; ++ct)
      b[ct] = *(const bf16x8*)&wT[((((col0 >> 4) + ct) * 8 + kk) * 4 + lq) * 128 + l15 * 8];
#pragma unroll
    for (int rt = 0; rt < 4; ++rt)
#pragma unroll
      for (int ct = 0; ct < 2; ++ct)
        acc[rt][ct] = SWAP ? mfma16(b[ct], a[rt], acc[rt][ct])
                           : mfma16(a[rt], b[ct], acc[rt][ct]);
  }
}

__global__ __launch_bounds__(512, 4)
void winattn_kernel(const float* __restrict__ x,
                    const unsigned short* __restrict__ wqkvT,
                    const unsigned short* __restrict__ woutT,
                    const float* __restrict__ bias64,
                    const float* __restrict__ b_out,
                    float* __restrict__ out) {
  __shared__ unsigned short smem[SMEM_ELTS];

  const int tid = threadIdx.x;
  const int lane = tid & 63;
  const int w = tid >> 6;        // wave id 0..7 == head id
  const int l15 = lane & 15;
  const int lq = lane >> 4;

  const int bid = blockIdx.x;
  const int win = bid & 255;
  const int img = bid >> 8;
  const int wy = win >> 4, wx = win & 15;

  unsigned short* x_lds  = smem;                 // phase 1-2: x; phase 3-4: oh
  unsigned short* oh_lds = smem;
  unsigned short* rt_buf = smem + OFF_RT + w * RT_ELEMS;   // wave-private

  const f32x4 zero4 = {0.f, 0.f, 0.f, 0.f};
  const size_t img_base = (size_t)img * 128 * 128 * 256;

  // ---------- phase 1: stage x window -> bf16 LDS (coalesced, 8 waves) ----------
  {
#pragma unroll
    for (int r = 0; r < 8; ++r) {
      int p = r * 8 + w;                 // pixel 0..63
      const float* src = x + img_base +
          (((size_t)(wy * 8 + (p >> 3)) * 128) + (wx * 8 + (p & 7))) * 256 + lane * 4;
      float4 v4 = *(const float4*)src;
      *(uint2*)&x_lds[p * XO + lane * 4] = pack4(v4.x, v4.y, v4.z, v4.w);
    }
  }
  __syncthreads();   // bar1

  // ---------- phase 2: q/k/v for this wave's head (cols w*32..+32) ----------
  // qf/kf[rt]: A/B-frag, (px rt*16+l15, feat lq*8..+8)
  // vf[ft][h2]: A-frag of vT, (feat ft*16+l15, kv px h2*32+lq*8..+8)
  bf16x8 qf[4], kf[4], vf[2][2];
  {
    f32x4 acc[4][2];
    // q chunk (swapped: feat rows, px cols)
    gemm32<true>(acc, x_lds, wqkvT, w * 32, l15, lq);
#pragma unroll
    for (int h2 = 0; h2 < 2; ++h2) {  // px halves through RT scratch
#pragma unroll
      for (int rr = 0; rr < 2; ++rr)
#pragma unroll
        for (int ct = 0; ct < 2; ++ct)
          *(uint2*)&rt_buf[(rr * 16 + l15) * RTS + ct * 16 + lq * 4] =
              pack4(acc[h2 * 2 + rr][ct][0], acc[h2 * 2 + rr][ct][1],
                    acc[h2 * 2 + rr][ct][2], acc[h2 * 2 + rr][ct][3]);
#pragma unroll
      for (int rr = 0; rr < 2; ++rr)
        qf[h2 * 2 + rr] = *(const bf16x8*)&rt_buf[(rr * 16 + l15) * RTS + lq * 8];
    }
    // k chunk
    gemm32<true>(acc, x_lds, wqkvT, 256 + w * 32, l15, lq);
#pragma unroll
    for (int h2 = 0; h2 < 2; ++h2) {
#pragma unroll
      for (int rr = 0; rr < 2; ++rr)
#pragma unroll
        for (int ct = 0; ct < 2; ++ct)
          *(uint2*)&rt_buf[(rr * 16 + l15) * RTS + ct * 16 + lq * 4] =
              pack4(acc[h2 * 2 + rr][ct][0], acc[h2 * 2 + rr][ct][1],
                    acc[h2 * 2 + rr][ct][2], acc[h2 * 2 + rr][ct][3]);
#pragma unroll
      for (int rr = 0; rr < 2; ++rr)
        kf[h2 * 2 + rr] = *(const bf16x8*)&rt_buf[(rr * 16 + l15) * RTS + lq * 8];
    }
    // v chunk (normal: px rows, feat cols); transpose via RT
    gemm32<false>(acc, x_lds, wqkvT, 512 + w * 32, l15, lq);
#pragma unroll
    for (int h2 = 0; h2 < 2; ++h2) {  // kv-px halves
#pragma unroll
      for (int rr = 0; rr < 2; ++rr)
#pragma unroll
        for (int ct = 0; ct < 2; ++ct)
          *(uint2*)&rt_buf[(ct * 16 + l15) * RTS + rr * 16 + lq * 4] =
              pack4(acc[h2 * 2 + rr][ct][0], acc[h2 * 2 + rr][ct][1],
                    acc[h2 * 2 + rr][ct][2], acc[h2 * 2 + rr][ct][3]);
#pragma unroll
      for (int ft = 0; ft < 2; ++ft)
        vf[ft][h2] = *(const bf16x8*)&rt_buf[(ft * 16 + l15) * RTS + lq * 8];
    }
  }
  __syncthreads();   // bar2: all x reads done -> oh region (overlays x) safe

  // ---------- phase 3: attention for head w, all 64 pixels ----------
#pragma unroll
  for (int it = 0; it < 4; ++it) {
    f32x4 bias4[4];
#pragma unroll
    for (int jt = 0; jt < 4; ++jt)
      bias4[jt] = *(const f32x4*)&bias64[(it * 16 + l15) * 64 + jt * 16 + lq * 4];
    // S^T = mfma(k, q): D[kv jt*16+lq*4+r][q px it*16+l15]
    f32x4 s[4];
#pragma unroll
    for (int jt = 0; jt < 4; ++jt)
      s[jt] = mfma16(kf[jt], qf[it], zero4);
    // p = exp2(s*ES + bias); row-sum over kv (regs + lq lanes)
    float rs = 0.f;
#pragma unroll
    for (int jt = 0; jt < 4; ++jt)
#pragma unroll
      for (int r = 0; r < 4; ++r) {
        s[jt][r] = __builtin_amdgcn_exp2f(s[jt][r] * EXPSCALE + bias4[jt][r]);
        rs += s[jt][r];
      }
    rs += __shfl_xor(rs, 16);
    rs += __shfl_xor(rs, 32);
    const float rinv = __builtin_amdgcn_rcpf(rs);

    // P -> wave-private scratch (P[q l15][kv]), packed b64
#pragma unroll
    for (int jt = 0; jt < 4; ++jt)
      *(uint2*)&rt_buf[l15 * PS + jt * 16 + lq * 4] =
          pack4(s[jt][0], s[jt][1], s[jt][2], s[jt][3]);
    const bf16x8 ap0 = *(const bf16x8*)&rt_buf[l15 * PS + lq * 8];
    const bf16x8 ap1 = *(const bf16x8*)&rt_buf[l15 * PS + 32 + lq * 8];

    // oh^T = mfma(vT, P^T): D[feat ft*16+lq*4+r][q px it*16+l15]
    f32x4 o0 = mfma16(vf[0][0], ap0, zero4);
    o0 = mfma16(vf[0][1], ap1, o0);
    f32x4 o1 = mfma16(vf[1][0], ap0, zero4);
    o1 = mfma16(vf[1][1], ap1, o1);

    // normalize + stage oh (px-major shared region, cols w*32..+32), b64
    *(uint2*)&oh_lds[(it * 16 + l15) * XO + w * 32 + lq * 4] =
        pack4(o0[0] * rinv, o0[1] * rinv, o0[2] * rinv, o0[3] * rinv);
    *(uint2*)&oh_lds[(it * 16 + l15) * XO + w * 32 + 16 + lq * 4] =
        pack4(o1[0] * rinv, o1[1] * rinv, o1[2] * rinv, o1[3] * rinv);
  }
  __syncthreads();   // bar3: oh complete

  // ---------- phase 4: out-proj (ofeat cols w*32..+32), K=256 GEMM + epilogue ----------
  {
    f32x4 ACC[4][2];
#pragma unroll
    for (int rt = 0; rt < 4; ++rt)
#pragma unroll
      for (int ct = 0; ct < 2; ++ct) ACC[rt][ct] = zero4;
#pragma unroll
    for (int kk = 0; kk < 8; ++kk) {
      bf16x8 a[4], b[2];
#pragma unroll
      for (int rt = 0; rt < 4; ++rt)
        a[rt] = *(const bf16x8*)&oh_lds[(rt * 16 + l15) * XO + kk * 32 + lq * 8];
#pragma unroll
      for (int ct = 0; ct < 2; ++ct)
        b[ct] = *(const bf16x8*)&woutT[(((w * 2 + ct) * 8 + kk) * 4 + lq) * 128 + l15 * 8];
#pragma unroll
      for (int rt = 0; rt < 4; ++rt)
#pragma unroll
        for (int ct = 0; ct < 2; ++ct)
          ACC[rt][ct] = mfma16(b[ct], a[rt], ACC[rt][ct]);   // D[ofeat][px]
    }
    // epilogue: D rows = ofeat w*32+ct*16+lq*4+r, cols = px rt*16+l15
#pragma unroll
    for (int rt = 0; rt < 4; ++rt) {
      const int p = rt * 16 + l15;
      float* orow = out + img_base +
          (((size_t)(wy * 8 + (p >> 3)) * 128) + (wx * 8 + (p & 7))) * 256;
#pragma unroll
      for (int ct = 0; ct < 2; ++ct) {
        const int n0 = w * 32 + ct * 16 + lq * 4;
        const f32x4 bo4 = *(const f32x4*)&b_out[n0];
        f32x4 st;
#pragma unroll
        for (int r = 0; r < 4; ++r) st[r] = ACC[rt][ct][r] + bo4[r];
        *(f32x4*)(orow + n0) = st;
      }
    }
  }
}

extern "C" void kernel_launch(void* const* d_in, const int* in_sizes, int n_in,
                              void* d_out, int out_size, void* d_ws, size_t ws_size,
                              hipStream_t stream) {
  const float* x       = (const float*)d_in[0];
  const float* w_qkv   = (const float*)d_in[1];
  const float* pos_emb = (const float*)d_in[2];
  const float* w_out   = (const float*)d_in[3];
  const float* b_out   = (const float*)d_in[4];
  float* out = (float*)d_out;

  unsigned short* wqkvT = (unsigned short*)d_ws;
  unsigned short* woutT = wqkvT + 768 * 256;
  float* bias64 = (float*)(woutT + 256 * 256);

  prep_kernel<<<96, 256, 0, stream>>>(w_qkv, w_out, pos_emb, wqkvT, woutT, bias64);
  winattn_kernel<<<2048, 512, 0, stream>>>(x, wqkvT, woutT, bias64, b_out, out);
}